// Round 8
// baseline (1052.874 us; speedup 1.0000x reference)
//
#include <hip/hip_runtime.h>

// Problem constants
#define E_TOT 8192
#define NB    32
#define H     128
#define EPG   256          // edges per graph (contiguous slots)

typedef __attribute__((ext_vector_type(8))) short bf16x8;
typedef __attribute__((ext_vector_type(4))) float f32x4;

__device__ __forceinline__ unsigned short bf16_rne(float f) {
    unsigned int u = __float_as_uint(f);
    unsigned int r = (u + 0x7FFFu + ((u >> 16) & 1u)) >> 16;
    return (unsigned short)r;
}
__device__ __forceinline__ float bf16_to_f32(unsigned short h) {
    return __uint_as_float(((unsigned int)h) << 16);
}
__device__ __forceinline__ void gload_lds16(const void* g, void* l) {
    __builtin_amdgcn_global_load_lds(
        (const __attribute__((address_space(1))) unsigned int*)g,
        (__attribute__((address_space(3))) unsigned int*)l, 16, 0, 0);
}

// ---------------------------------------------------------------------------
// Z layout per stage: Z[v][k2], k2 = 2*KH shorts; KH = 34*CIN.
//   k(d,i) = d*CIN + i  (d<32: conv w/ ea coef; d=32: bias-row; d=33: root).
//   hi half [0,KH), lo half [KH,2KH).  h = Z @ Bt^T (+bias), 3-region
//   split-bf16 virtual K = 3*KH. (R7: verified EXACT, absmax 0.0)
// ---------------------------------------------------------------------------

// build_Bt_z: Bt[o][k2] = [Wh(KH) | Wl(KH)], o = output col 0..127.
template<int CIN>
__global__ __launch_bounds__(256)
void build_Bt_z(const float* __restrict__ nnw, const float* __restrict__ nnb,
                const float* __restrict__ root, unsigned short* __restrict__ Bt)
{
    constexpr int KH = 34 * CIN;
    constexpr int K2 = 2 * KH;
    const int d  = blockIdx.x;
    const int i0 = blockIdx.y * 32;
    const float* __restrict__ W =
        (d < 32) ? (nnw + (size_t)d * CIN * 128) : ((d == 32) ? nnb : root);

    __shared__ unsigned short LHI[128][40];
    __shared__ unsigned short LLO[128][40];

    for (int idx = threadIdx.x; idx < 32 * 128; idx += 256) {
        const int ii = idx >> 7, o = idx & 127;
        const float val = W[(size_t)(i0 + ii) * 128 + o];
        const unsigned short h = bf16_rne(val);
        const unsigned short l = bf16_rne(val - bf16_to_f32(h));
        LHI[o][ii] = h; LLO[o][ii] = l;
    }
    __syncthreads();

    const int o    = threadIdx.x & 127;
    const int half = threadIdx.x >> 7;
    unsigned short* dst = Bt + (size_t)o * K2 + d * CIN + i0;
    if (half == 0) {
        const uint4* hs = (const uint4*)&LHI[o][0];
        uint4* p = (uint4*)dst;
        p[0] = hs[0]; p[1] = hs[1]; p[2] = hs[2]; p[3] = hs[3];
    } else {
        const uint4* ls = (const uint4*)&LLO[o][0];
        uint4* q = (uint4*)(dst + KH);
        q[0] = ls[0]; q[1] = ls[1]; q[2] = ls[2]; q[3] = ls[3];
    }
}

// build_rootA: stage-1 root block of Z1 = split(x). Grid 4096, 64 threads.
__global__ __launch_bounds__(64)
void build_rootA(const float* __restrict__ x, unsigned short* __restrict__ Z)
{
    constexpr int KH = 34 * 64, K2 = 2 * KH, ROFF = 33 * 64;
    const int v = blockIdx.x, i = threadIdx.x;
    const float val = x[(size_t)v * 64 + i];
    const unsigned short h = bf16_rne(val);
    const unsigned short l = bf16_rne(val - bf16_to_f32(h));
    unsigned short* zr = Z + (size_t)v * K2 + ROFF + i;
    zr[0] = h; zr[KH] = l;
}

// ---------------------------------------------------------------------------
// zbuild v2: block (graph g, d). Z[v, d-block] = sum_{e->v} coef(e,d)*x[src,:]
// Branch-free, register-chunked (8 edges/round), uint4 staging/writeback.
// Grid (NB, 33), 256 threads.
// ---------------------------------------------------------------------------
template<int NPG, int CIN>
__global__ __launch_bounds__(256)
void zbuild(unsigned short* __restrict__ Z,
            const float* __restrict__ ea,     // [E,32]
            const int*   __restrict__ esrc,   // [E], -1 invalid
            const int*   __restrict__ edst)
{
    constexpr int KH = 34 * CIN, K2 = 2 * KH, ROFF = 33 * CIN;
    constexpr int NU = NPG * CIN / 8;          // uint4 units
    __shared__ float xt[NPG * CIN];
    __shared__ float Zs[NPG * CIN];
    __shared__ float cE[EPG];
    __shared__ int   sE[EPG];
    __shared__ int   dE[EPG];

    const int tid = threadIdx.x;
    const int g = blockIdx.x, d = blockIdx.y;

    // ---- stage x from root block (uint4 hi+lo, decode 8 at a time) ----
    for (int u = tid; u < NU; u += 256) {
        const int v = u / (CIN / 8), seg = u % (CIN / 8);
        const unsigned short* zr = Z + (size_t)(g * NPG + v) * K2 + ROFF + seg * 8;
        const uint4 hi = *(const uint4*)zr;
        const uint4 lo = *(const uint4*)(zr + KH);
        const unsigned short* hp = (const unsigned short*)&hi;
        const unsigned short* lp = (const unsigned short*)&lo;
        float* o = &xt[v * CIN + seg * 8];
        float* z = &Zs[v * CIN + seg * 8];
        #pragma unroll
        for (int j = 0; j < 8; ++j) {
            o[j] = bf16_to_f32(hp[j]) + bf16_to_f32(lp[j]);
            z[j] = 0.0f;
        }
    }
    // ---- edge params (c=0 for invalid or when masked) ----
    {
        const int e = g * EPG + tid;
        const int s = esrc[e];
        const bool valid = (s >= 0);
        sE[tid] = valid ? (s - g * NPG) * CIN : 0;
        dE[tid] = valid ? (edst[e] - g * NPG) * CIN : 0;
        cE[tid] = valid ? ((d < 32) ? ea[(size_t)e * 32 + d] : 1.0f) : 0.0f;
    }
    __syncthreads();

    // ---- branch-free scatter, 8 edges per register chunk ----
    constexpr int EPB = 256 / CIN;      // edges per pass (4 or 2)
    const int esub = tid / CIN;
    const int i    = tid % CIN;
    for (int eb = 0; eb < EPG; eb += 8 * EPB) {
        float c_r[8]; int s_r[8], d_r[8];
        #pragma unroll
        for (int j = 0; j < 8; ++j) {
            const int e = eb + j * EPB + esub;
            c_r[j] = cE[e]; s_r[j] = sE[e]; d_r[j] = dE[e];
        }
        float v_r[8];
        #pragma unroll
        for (int j = 0; j < 8; ++j) v_r[j] = c_r[j] * xt[s_r[j] + i];
        #pragma unroll
        for (int j = 0; j < 8; ++j) atomicAdd(&Zs[d_r[j] + i], v_r[j]);
    }
    __syncthreads();

    // ---- split-bf16 writeback, uint4 stores ----
    for (int u = tid; u < NU; u += 256) {
        const int v = u / (CIN / 8), seg = u % (CIN / 8);
        const float* z = &Zs[v * CIN + seg * 8];
        unsigned short hs[8], ls[8];
        #pragma unroll
        for (int j = 0; j < 8; ++j) {
            const unsigned short h = bf16_rne(z[j]);
            hs[j] = h;
            ls[j] = bf16_rne(z[j] - bf16_to_f32(h));
        }
        unsigned short* zw = Z + (size_t)(g * NPG + v) * K2 + d * CIN + seg * 8;
        *(uint4*)zw        = *(const uint4*)hs;
        *(uint4*)(zw + KH) = *(const uint4*)ls;
    }
}

// ---------------------------------------------------------------------------
// gemm_z v2: partial[ks][m, o] = A[m, kslice] @ Bt[o, kslice]^T, virtual
// K = 3*KH (3-region split-bf16). 256 thr (4 waves), M-tile 64 (one 16-row
// strip per wave), N=128 (8 frags). Grid (M/64, KS); KS chosen so each block
// runs exactly NC/KS = 17 k-chunks.
// ---------------------------------------------------------------------------
template<int KH, int KS>
__global__ __launch_bounds__(256)
void gemm_z(const unsigned short* __restrict__ A,   // [M, 2*KH]
            const unsigned short* __restrict__ B,   // [128, 2*KH]
            float* __restrict__ part, int M)
{
    constexpr int K2  = 2 * KH;
    constexpr int CH  = KH / 32;     // 32-k chunks per region
    constexpr int NC  = 3 * CH;      // virtual chunks
    constexpr int CPB = NC / KS;     // chunks per block (= 17)
    __shared__ unsigned short Alds[64 * 32];
    __shared__ unsigned short Blds[128 * 32];

    const int tid  = threadIdx.x;
    const int lane = tid & 63;
    const int w    = tid >> 6;       // wave 0..3
    const int m0   = blockIdx.x * 64;
    const int ks   = blockIdx.y;

    f32x4 acc[8];
    #pragma unroll
    for (int f = 0; f < 8; ++f) acc[f] = (f32x4)(0.0f);

    const int arow = lane >> 2;      // row within 16-row chunk
    const int aseg = lane & 3;       // 16B segment within 64B row
    const int koff = (lane >> 4) * 8;
    const int mrow = lane & 15;

    for (int kk = ks * CPB; kk < (ks + 1) * CPB; ++kk) {
        const int r = kk / CH, c = kk % CH;
        const int a_k = (r < 2) ? c * 32 : KH + c * 32;
        const int b_k = (r == 1) ? KH + c * 32 : c * 32;

        __syncthreads();   // prior ds_reads done before overwrite
        gload_lds16(A + (size_t)(m0 + w * 16 + arow) * K2 + a_k + aseg * 8,
                    &Alds[w * 512]);
        #pragma unroll
        for (int t = 0; t < 2; ++t)
            gload_lds16(B + (size_t)(w * 32 + t * 16 + arow) * K2 + b_k + aseg * 8,
                        &Blds[w * 1024 + t * 512]);
        __syncthreads();   // drains vmcnt per barrier semantics

        const bf16x8 a = *(const bf16x8*)&Alds[(w * 16 + mrow) * 32 + koff];
        #pragma unroll
        for (int f = 0; f < 8; ++f) {
            const bf16x8 b = *(const bf16x8*)&Blds[(f * 16 + mrow) * 32 + koff];
            acc[f] = __builtin_amdgcn_mfma_f32_16x16x32_bf16(a, b, acc[f], 0, 0, 0);
        }
    }

    const int crow = (lane >> 4) * 4;
    const int ccol = lane & 15;
    #pragma unroll
    for (int f = 0; f < 8; ++f) {
        #pragma unroll
        for (int rr = 0; rr < 4; ++rr)
            part[((size_t)ks * M + m0 + w * 16 + crow + rr) * H + f * 16 + ccol]
                = acc[f][rr];
    }
}

// ---------------------------------------------------------------------------
// reduce_stats: h = sum_ks partial + bias; column sums/sumsq atomically.
// ---------------------------------------------------------------------------
__global__ __launch_bounds__(256)
void reduce_stats(const float* __restrict__ part, int M, int KS,
                  const float* __restrict__ bias, float* __restrict__ h,
                  float* __restrict__ gsum, float* __restrict__ gsumsq)
{
    const int tid   = threadIdx.x;
    const int col   = tid & 127;
    const int rhalf = tid >> 7;
    float s = 0.f, sq = 0.f;
    for (int r = blockIdx.x * 2 + rhalf; r < M; r += 128) {
        float v = bias[col];
        for (int ks = 0; ks < KS; ++ks)
            v += part[((size_t)ks * M + r) * H + col];
        h[(size_t)r * H + col] = v;
        s += v; sq += v * v;
    }
    __shared__ float sh[256];
    sh[tid] = s;  __syncthreads();
    if (rhalf == 0) s += sh[tid + 128];
    __syncthreads();
    sh[tid] = sq; __syncthreads();
    if (rhalf == 0) {
        sq += sh[tid + 128];
        atomicAdd(&gsum[col], s);
        atomicAdd(&gsumsq[col], sq);
    }
}

// ---------------------------------------------------------------------------
// fused_pool: one block per graph. BN (on-the-fly) + ReLU + score + top-k +
// next-stage Z root-block emission (split bf16) + edge remap.
// ---------------------------------------------------------------------------
__global__ __launch_bounds__(256)
void fused_pool(const float* __restrict__ h,
                const float* __restrict__ gsum, const float* __restrict__ gsumsq,
                float n_f,
                const float* __restrict__ gamma, const float* __restrict__ beta,
                const float* __restrict__ pw,
                int npg, int k,
                const int* __restrict__ esrc_in, const int* __restrict__ edst_in,
                int* __restrict__ esrc_out, int* __restrict__ edst_out,
                unsigned short* __restrict__ Zout, int K2out)
{
    const int g   = blockIdx.x;
    const int tid = threadIdx.x;
    const int wv  = tid >> 6;
    const int ln  = tid & 63;
    const int KHout = K2out >> 1;
    const int ROFF  = 33 * 128;   // next stage CIN = 128

    __shared__ float muL[128], rsL[128], gmL[128], btL[128], pwL[128];
    __shared__ float scoreL[128], red[128];
    __shared__ int   mapL[128];
    __shared__ float sinv;

    if (tid < 128) {
        const float mu  = gsum[tid] / n_f;
        const float var = gsumsq[tid] / n_f - mu * mu;
        muL[tid] = mu;
        rsL[tid] = rsqrtf(var + 1e-5f);
        gmL[tid] = gamma[tid];
        btL[tid] = beta[tid];
        const float p = pw[tid];
        pwL[tid] = p;
        red[tid] = p * p;
    }
    __syncthreads();
    for (int off = 64; off > 0; off >>= 1) {
        if (tid < off) red[tid] += red[tid + off];
        __syncthreads();
    }
    if (tid == 0) sinv = rsqrtf(red[0]);
    __syncthreads();

    for (int r = wv; r < npg; r += 4) {
        const float* hr = h + (size_t)(g * npg + r) * H;
        float p = 0.f;
        #pragma unroll
        for (int half = 0; half < 2; ++half) {
            const int c = ln + half * 64;
            const float y = fmaxf(gmL[c] * (hr[c] - muL[c]) * rsL[c] + btL[c], 0.f);
            p += y * pwL[c];
        }
        #pragma unroll
        for (int off = 32; off > 0; off >>= 1)
            p += __shfl_down(p, off, 64);
        if (ln == 0) scoreL[r] = tanhf(p * sinv);
    }
    __syncthreads();

    if (tid < npg) {
        const float si = scoreL[tid];
        int cnt = 0;
        for (int j = 0; j < npg; ++j) {
            const float sj = scoreL[j];
            cnt += (sj > si) || (sj == si && j < tid);
        }
        mapL[tid] = (cnt < k) ? cnt : -1;
    }
    __syncthreads();

    // emit next-stage root block rows (split bf16)
    for (int r = wv; r < npg; r += 4) {
        const int nr = mapL[r];
        if (nr < 0) continue;
        const float sc = scoreL[r];
        const float* hr = h + (size_t)(g * npg + r) * H;
        unsigned short* base = Zout + (size_t)(g * k + nr) * K2out + ROFF;
        #pragma unroll
        for (int half = 0; half < 2; ++half) {
            const int c = ln + half * 64;
            const float y = fmaxf(gmL[c] * (hr[c] - muL[c]) * rsL[c] + btL[c], 0.f) * sc;
            const unsigned short hb = bf16_rne(y);
            const unsigned short lb = bf16_rne(y - bf16_to_f32(hb));
            base[c] = hb; base[KHout + c] = lb;
        }
    }

    // remap this graph's 256 edges
    {
        const int e = g * EPG + tid;
        const int s = esrc_in[e];
        int ns = -1, nd = -1;
        if (s >= 0) {
            const int ms = mapL[s - g * npg];
            const int md = mapL[edst_in[e] - g * npg];
            if (ms >= 0 && md >= 0) { ns = g * k + ms; nd = g * k + md; }
        }
        esrc_out[e] = ns; edst_out[e] = nd;
    }
}

// ---------------------------------------------------------------------------
// fused_pool_final: stage-3 pool (npg=32,k=16) + mean-pool + MLP + sigmoid.
// ---------------------------------------------------------------------------
__global__ __launch_bounds__(256)
void fused_pool_final(const float* __restrict__ h,
                      const float* __restrict__ gsum, const float* __restrict__ gsumsq,
                      float n_f,
                      const float* __restrict__ gamma, const float* __restrict__ beta,
                      const float* __restrict__ pw,
                      const float* __restrict__ lin1_w, const float* __restrict__ lin1_b,
                      const float* __restrict__ lin2_w, const float* __restrict__ lin2_b,
                      float* __restrict__ out)
{
    const int g   = blockIdx.x;
    const int tid = threadIdx.x;
    const int wv  = tid >> 6;
    const int ln  = tid & 63;
    const int npg = 32, k = 16;

    __shared__ float muL[128], rsL[128], gmL[128], btL[128], pwL[128];
    __shared__ float scoreL[32], red[128], gmean[128], h1c[64];
    __shared__ int   mapL[32];
    __shared__ float sinv;

    if (tid < 128) {
        const float mu  = gsum[tid] / n_f;
        const float var = gsumsq[tid] / n_f - mu * mu;
        muL[tid] = mu;
        rsL[tid] = rsqrtf(var + 1e-5f);
        gmL[tid] = gamma[tid];
        btL[tid] = beta[tid];
        const float p = pw[tid];
        pwL[tid] = p;
        red[tid] = p * p;
    }
    __syncthreads();
    for (int off = 64; off > 0; off >>= 1) {
        if (tid < off) red[tid] += red[tid + off];
        __syncthreads();
    }
    if (tid == 0) sinv = rsqrtf(red[0]);
    __syncthreads();

    for (int r = wv; r < npg; r += 4) {
        const float* hr = h + (size_t)(g * npg + r) * H;
        float p = 0.f;
        #pragma unroll
        for (int half = 0; half < 2; ++half) {
            const int c = ln + half * 64;
            const float y = fmaxf(gmL[c] * (hr[c] - muL[c]) * rsL[c] + btL[c], 0.f);
            p += y * pwL[c];
        }
        #pragma unroll
        for (int off = 32; off > 0; off >>= 1)
            p += __shfl_down(p, off, 64);
        if (ln == 0) scoreL[r] = tanhf(p * sinv);
    }
    __syncthreads();

    if (tid < npg) {
        const float si = scoreL[tid];
        int cnt = 0;
        for (int j = 0; j < npg; ++j) {
            const float sj = scoreL[j];
            cnt += (sj > si) || (sj == si && j < tid);
        }
        mapL[tid] = (cnt < k) ? cnt : -1;
    }
    __syncthreads();

    if (tid < 128) {
        float acc = 0.f;
        for (int r = 0; r < npg; ++r) {
            if (mapL[r] < 0) continue;
            const float hv = h[(size_t)(g * npg + r) * H + tid];
            const float y  = fmaxf(gmL[tid] * (hv - muL[tid]) * rsL[tid] + btL[tid], 0.f);
            acc += y * scoreL[r];
        }
        gmean[tid] = acc * (1.0f / 16.0f);
    }
    __syncthreads();

    if (tid < 64) {
        float acc = lin1_b[tid];
        for (int o = 0; o < 128; ++o) acc += gmean[o] * lin1_w[o * 64 + tid];
        h1c[tid] = fmaxf(acc, 0.f);
    }
    __syncthreads();
    if (tid == 0) {
        float z = lin2_b[0];
        for (int j = 0; j < 64; ++j) z += h1c[j] * lin2_w[j];
        out[g] = 1.0f / (1.0f + expf(-z));
    }
}

extern "C" void kernel_launch(void* const* d_in, const int* in_sizes, int n_in,
                              void* d_out, int out_size, void* d_ws, size_t ws_size,
                              hipStream_t stream)
{
    const float* x        = (const float*)d_in[0];
    const int*   ei       = (const int*)  d_in[1];
    const float* eattr    = (const float*)d_in[2];
    const float* nn1_w    = (const float*)d_in[4];
    const float* nn1_b    = (const float*)d_in[5];
    const float* root1    = (const float*)d_in[6];
    const float* bias1    = (const float*)d_in[7];
    const float* nn2_w    = (const float*)d_in[8];
    const float* nn2_b    = (const float*)d_in[9];
    const float* root2    = (const float*)d_in[10];
    const float* bias2    = (const float*)d_in[11];
    const float* nn3_w    = (const float*)d_in[12];
    const float* nn3_b    = (const float*)d_in[13];
    const float* root3    = (const float*)d_in[14];
    const float* bias3    = (const float*)d_in[15];
    const float* gamma1   = (const float*)d_in[16];
    const float* beta1    = (const float*)d_in[17];
    const float* gamma2   = (const float*)d_in[18];
    const float* beta2    = (const float*)d_in[19];
    const float* gamma3   = (const float*)d_in[20];
    const float* beta3    = (const float*)d_in[21];
    const float* pw1      = (const float*)d_in[22];
    const float* pw2      = (const float*)d_in[23];
    const float* pw3      = (const float*)d_in[24];
    const float* lin1_w   = (const float*)d_in[25];
    const float* lin1_b   = (const float*)d_in[26];
    const float* lin2_w   = (const float*)d_in[27];
    const float* lin2_b   = (const float*)d_in[28];

    const int* ei_src = ei;
    const int* ei_dst = ei + E_TOT;

    // KH1 = 2176 (K2=4352), KH23 = 4352 (K2=8704); NC1 = 204, NC23 = 408.
    char* wp = (char*)d_ws;
    auto alloc = [&](size_t bytes) { char* p = wp; wp += (bytes + 255) & ~(size_t)255; return p; };
    float* h1    = (float*)alloc(4096 * 128 * 4);
    float* h2    = (float*)alloc(2048 * 128 * 4);
    float* h3    = (float*)alloc(1024 * 128 * 4);
    int*   src1  = (int*)alloc(E_TOT * 4);
    int*   dst1  = (int*)alloc(E_TOT * 4);
    int*   src2  = (int*)alloc(E_TOT * 4);
    int*   dst2  = (int*)alloc(E_TOT * 4);
    float* stats = (float*)alloc(6 * 128 * 4);
    unsigned short* Z1  = (unsigned short*)alloc((size_t)4096 * 4352 * 2);
    unsigned short* Z2  = (unsigned short*)alloc((size_t)2048 * 8704 * 2);
    unsigned short* Z3  = (unsigned short*)alloc((size_t)1024 * 8704 * 2);
    unsigned short* Bt1 = (unsigned short*)alloc((size_t)128 * 4352 * 2);
    unsigned short* Bt2 = (unsigned short*)alloc((size_t)128 * 8704 * 2);
    unsigned short* Bt3 = (unsigned short*)alloc((size_t)128 * 8704 * 2);
    float* part = (float*)alloc((size_t)24 * 2048 * 128 * 4);   // max over stages

    hipMemsetAsync(stats, 0, 6 * 128 * sizeof(float), stream);

    // Setup: weights + stage-1 root features
    build_Bt_z<64> <<<dim3(34, 2), 256, 0, stream>>>(nn1_w, nn1_b, root1, Bt1);
    build_Bt_z<128><<<dim3(34, 4), 256, 0, stream>>>(nn2_w, nn2_b, root2, Bt2);
    build_Bt_z<128><<<dim3(34, 4), 256, 0, stream>>>(nn3_w, nn3_b, root3, Bt3);
    build_rootA<<<4096, 64, 0, stream>>>(x, Z1);

    // ---- Stage 1 ----
    zbuild<128, 64><<<dim3(NB, 33), 256, 0, stream>>>(Z1, eattr, ei_src, ei_dst);
    gemm_z<2176, 12><<<dim3(4096 / 64, 12), 256, 0, stream>>>(Z1, Bt1, part, 4096);
    reduce_stats<<<64, 256, 0, stream>>>(part, 4096, 12, bias1, h1, stats, stats + 128);
    fused_pool<<<NB, 256, 0, stream>>>(h1, stats, stats + 128, 4096.0f,
                                       gamma1, beta1, pw1, 128, 64,
                                       ei_src, ei_dst, src1, dst1, Z2, 8704);

    // ---- Stage 2 ----
    zbuild<64, 128><<<dim3(NB, 33), 256, 0, stream>>>(Z2, eattr, src1, dst1);
    gemm_z<4352, 24><<<dim3(2048 / 64, 24), 256, 0, stream>>>(Z2, Bt2, part, 2048);
    reduce_stats<<<64, 256, 0, stream>>>(part, 2048, 24, bias2, h2, stats + 256, stats + 384);
    fused_pool<<<NB, 256, 0, stream>>>(h2, stats + 256, stats + 384, 2048.0f,
                                       gamma2, beta2, pw2, 64, 32,
                                       src1, dst1, src2, dst2, Z3, 8704);

    // ---- Stage 3 ----
    zbuild<32, 128><<<dim3(NB, 33), 256, 0, stream>>>(Z3, eattr, src2, dst2);
    gemm_z<4352, 24><<<dim3(1024 / 64, 24), 256, 0, stream>>>(Z3, Bt3, part, 1024);
    reduce_stats<<<64, 256, 0, stream>>>(part, 1024, 24, bias3, h3, stats + 512, stats + 640);
    fused_pool_final<<<NB, 256, 0, stream>>>(h3, stats + 512, stats + 640, 1024.0f,
                                             gamma3, beta3, pw3,
                                             lin1_w, lin1_b, lin2_w, lin2_b,
                                             (float*)d_out);
}

// Round 9
// 342.795 us; speedup vs baseline: 3.0714x; 3.0714x over previous
//
#include <hip/hip_runtime.h>

// Problem constants
#define E_TOT 8192
#define NB    32
#define H     128
#define EPG   256          // edges per graph (contiguous slots)
#define YD    33           // Y d-blocks (d<32 conv, d=32 edge-MLP bias row)
#define YCOLS (YD * H)     // 4224

typedef __attribute__((ext_vector_type(8))) short bf16x8;
typedef __attribute__((ext_vector_type(4))) float f32x4;

__device__ __forceinline__ unsigned short bf16_rne(float f) {
    unsigned int u = __float_as_uint(f);
    unsigned int r = (u + 0x7FFFu + ((u >> 16) & 1u)) >> 16;
    return (unsigned short)r;
}
__device__ __forceinline__ float bf16_to_f32(unsigned short h) {
    return __uint_as_float(((unsigned int)h) << 16);
}
__device__ __forceinline__ void gload_lds16(const void* g, void* l) {
    __builtin_amdgcn_global_load_lds(
        (const __attribute__((address_space(1))) unsigned int*)g,
        (__attribute__((address_space(3))) unsigned int*)l, 16, 0, 0);
}

// ---------------------------------------------------------------------------
// build_A: A[v] = [xh(CIN) | xl(CIN)] split-bf16 (K2 = 2*CIN). [R6-verified]
// ---------------------------------------------------------------------------
template<int CIN>
__global__ __launch_bounds__(128)
void build_A(const float* __restrict__ x, unsigned short* __restrict__ A)
{
    const int v = blockIdx.x;
    unsigned short* row = A + (size_t)v * (2 * CIN);
    for (int i = threadIdx.x; i < CIN; i += 128) {
        const float val = x[(size_t)v * CIN + i];
        const unsigned short h = bf16_rne(val);
        const unsigned short l = bf16_rne(val - bf16_to_f32(h));
        row[i] = h; row[CIN + i] = l;
    }
}

// ---------------------------------------------------------------------------
// build_Bt: Bt[n = d*128+o] = [wh(CIN) | wl(CIN)]  (d<32: nn_w, 32: nn_b,
// 33: root). Grid (34, CIN/32), 256 threads. [R6-verified]
// ---------------------------------------------------------------------------
template<int CIN>
__global__ __launch_bounds__(256)
void build_Bt(const float* __restrict__ nnw, const float* __restrict__ nnb,
              const float* __restrict__ root, unsigned short* __restrict__ Bt)
{
    const int d  = blockIdx.x;
    const int i0 = blockIdx.y * 32;
    const float* __restrict__ W =
        (d < 32) ? (nnw + (size_t)d * CIN * 128) : ((d == 32) ? nnb : root);

    __shared__ unsigned short LHI[128][40];
    __shared__ unsigned short LLO[128][40];

    for (int idx = threadIdx.x; idx < 32 * 128; idx += 256) {
        const int ii = idx >> 7, o = idx & 127;
        const float val = W[(size_t)(i0 + ii) * 128 + o];
        const unsigned short h = bf16_rne(val);
        const unsigned short l = bf16_rne(val - bf16_to_f32(h));
        LHI[o][ii] = h; LLO[o][ii] = l;
    }
    __syncthreads();

    const int o    = threadIdx.x & 127;
    const int half = threadIdx.x >> 7;
    unsigned short* dst = Bt + (size_t)(d * 128 + o) * (2 * CIN);
    if (half == 0) {
        const uint4* hs = (const uint4*)&LHI[o][0];
        uint4* p = (uint4*)(dst + i0);
        p[0] = hs[0]; p[1] = hs[1]; p[2] = hs[2]; p[3] = hs[3];
    } else {
        const uint4* ls = (const uint4*)&LLO[o][0];
        uint4* q = (uint4*)(dst + CIN + i0);
        q[0] = ls[0]; q[1] = ls[1]; q[2] = ls[2]; q[3] = ls[3];
    }
}

// ---------------------------------------------------------------------------
// ygemm2: 128x256 bf16-MFMA tile (2 d-blocks per block share the A tile).
// Stored K2 = 2*CIN ([xh|xl] x [wh|wl]); virtual K = 3*CIN via region remap
// (r0: h*h, r1: h*l, r2: l*h) — exact-verified in R7.
// Epilogue: d-block = 2*blockIdx.y + wn; d<33 -> Y[:, d, :];
//           d==33 (root) -> h = acc + bias (init before contract dispatch).
// Grid (M/128, 17), 256 threads (4 waves, 2x2; each wave 64 rows x 128 cols).
// ---------------------------------------------------------------------------
template<int CIN>
__global__ __launch_bounds__(256)
void ygemm2(const unsigned short* __restrict__ A,   // [M, 2*CIN]
            const unsigned short* __restrict__ Bt,  // [34*128, 2*CIN]
            float* __restrict__ Y,                  // [M, 33*128]
            const float* __restrict__ bias,         // [128]
            float* __restrict__ h)                  // [M, 128]
{
    constexpr int K2 = 2 * CIN;
    constexpr int CH = CIN / 32;       // 32-k chunks per region
    constexpr int NC = 3 * CH;         // virtual chunks (6 or 12)
    __shared__ unsigned short Alds[128 * 32];
    __shared__ unsigned short Blds[256 * 32];

    const int tid  = threadIdx.x;
    const int lane = tid & 63;
    const int w    = tid >> 6;
    const int wm = w >> 1, wn = w & 1;
    const int v0 = blockIdx.x * 128;
    const int n0 = blockIdx.y * 256;   // Bt row base (2 d-blocks)

    f32x4 acc[4][8];
    #pragma unroll
    for (int i = 0; i < 4; ++i)
        #pragma unroll
        for (int j = 0; j < 8; ++j)
            acc[i][j] = (f32x4)(0.0f);

    const int srow = lane >> 2;        // staging row within 16-row chunk
    const int sseg = (lane & 3) * 8;   // staging seg (shorts)
    const int koff = (lane >> 4) * 8;  // frag k offset
    const int mrow = lane & 15;

    for (int kk = 0; kk < NC; ++kk) {
        const int r = kk / CH, c = kk % CH;
        const int a_k = (r < 2) ? c * 32 : CIN + c * 32;
        const int b_k = (r == 1) ? CIN + c * 32 : c * 32;

        __syncthreads();   // prior ds_reads done before overwrite
        #pragma unroll
        for (int t = 0; t < 2; ++t) {
            const int ch = w * 2 + t;  // A chunks: 8 x 16 rows
            gload_lds16(A + (size_t)(v0 + ch * 16 + srow) * K2 + a_k + sseg,
                        &Alds[ch * 512]);
        }
        #pragma unroll
        for (int t = 0; t < 4; ++t) {
            const int ch = w * 4 + t;  // B chunks: 16 x 16 rows
            gload_lds16(Bt + (size_t)(n0 + ch * 16 + srow) * K2 + b_k + sseg,
                        &Blds[ch * 512]);
        }
        __syncthreads();   // drains vmcnt per barrier semantics

        bf16x8 a[4], b[8];
        #pragma unroll
        for (int f = 0; f < 4; ++f)
            a[f] = *(const bf16x8*)&Alds[(wm * 64 + f * 16 + mrow) * 32 + koff];
        #pragma unroll
        for (int f = 0; f < 8; ++f)
            b[f] = *(const bf16x8*)&Blds[(wn * 128 + f * 16 + mrow) * 32 + koff];
        #pragma unroll
        for (int fm = 0; fm < 4; ++fm)
            #pragma unroll
            for (int fn = 0; fn < 8; ++fn)
                acc[fm][fn] = __builtin_amdgcn_mfma_f32_16x16x32_bf16(
                    a[fm], b[fn], acc[fm][fn], 0, 0, 0);
    }

    // epilogue (C/D: col=lane&15, row=(lane>>4)*4+r — verified layout)
    const int crow = (lane >> 4) * 4;
    const int ccol = lane & 15;
    const int dblk = blockIdx.y * 2 + wn;   // 0..33
    if (dblk == YD) {   // root block -> h = acc + bias
        #pragma unroll
        for (int fm = 0; fm < 4; ++fm) {
            const int gr = v0 + wm * 64 + fm * 16 + crow;
            #pragma unroll
            for (int fn = 0; fn < 8; ++fn) {
                const int col = fn * 16 + ccol;
                const float bv = bias[col];
                #pragma unroll
                for (int rr = 0; rr < 4; ++rr)
                    h[(size_t)(gr + rr) * H + col] = acc[fm][fn][rr] + bv;
            }
        }
    } else {
        #pragma unroll
        for (int fm = 0; fm < 4; ++fm) {
            const int gr = v0 + wm * 64 + fm * 16 + crow;
            #pragma unroll
            for (int fn = 0; fn < 8; ++fn) {
                const size_t gc = (size_t)dblk * H + fn * 16 + ccol;
                #pragma unroll
                for (int rr = 0; rr < 4; ++rr)
                    Y[(size_t)(gr + rr) * YCOLS + gc] = acc[fm][fn][rr];
            }
        }
    }
}

// ---------------------------------------------------------------------------
// contract_edges: h[dst[e], :] += sum_{d<32} ea[e,d]*Y[src[e],d,:] + Y[src,32,:]
// One 32-lane group per edge, float4 per lane. [R4-verified]
// ---------------------------------------------------------------------------
__global__ __launch_bounds__(256)
void contract_edges(const float* __restrict__ Y,
                    const float* __restrict__ ea,
                    const int*   __restrict__ esrc,
                    const int*   __restrict__ edst,
                    float*       __restrict__ agg)
{
    const int grp = threadIdx.x >> 5;
    const int l5  = threadIdx.x & 31;
    const int e   = blockIdx.x * 8 + grp;
    const int s   = esrc[e];
    if (s < 0) return;

    const float* yb  = Y + (size_t)s * YCOLS + l5 * 4;
    const float* ear = ea + (size_t)e * 32;

    float4 acc = *reinterpret_cast<const float4*>(yb + 32 * H);   // bias row
    #pragma unroll 8
    for (int dd = 0; dd < 32; ++dd) {
        const float c = ear[dd];
        const float4 y = *reinterpret_cast<const float4*>(yb + dd * H);
        acc.x += c * y.x; acc.y += c * y.y; acc.z += c * y.z; acc.w += c * y.w;
    }
    float* out = agg + (size_t)edst[e] * H + l5 * 4;
    atomicAdd(out + 0, acc.x);
    atomicAdd(out + 1, acc.y);
    atomicAdd(out + 2, acc.z);
    atomicAdd(out + 3, acc.w);
}

// Column sums / sumsq over n rows of h, atomically accumulated.
__global__ __launch_bounds__(256)
void bn_stats(const float* __restrict__ h, int n,
              float* __restrict__ gsum, float* __restrict__ gsumsq)
{
    const int tid   = threadIdx.x;
    const int col   = tid & 127;
    const int rhalf = tid >> 7;
    float s = 0.f, sq = 0.f;
    for (int r = blockIdx.x * 2 + rhalf; r < n; r += gridDim.x * 2) {
        float v = h[(size_t)r * H + col];
        s += v; sq += v * v;
    }
    __shared__ float sh[256];
    sh[tid] = s;  __syncthreads();
    if (rhalf == 0) s += sh[tid + 128];
    __syncthreads();
    sh[tid] = sq; __syncthreads();
    if (rhalf == 0) {
        sq += sh[tid + 128];
        atomicAdd(&gsum[col], s);
        atomicAdd(&gsumsq[col], sq);
    }
}

// ---------------------------------------------------------------------------
// fused_pool: one block per graph. BN + ReLU + score + top-k + next-stage
// A' emission ([yh|yl], K2=256) + edge remap. [R6-verified]
// ---------------------------------------------------------------------------
__global__ __launch_bounds__(256)
void fused_pool(const float* __restrict__ h,
                const float* __restrict__ gsum, const float* __restrict__ gsumsq,
                float n_f,
                const float* __restrict__ gamma, const float* __restrict__ beta,
                const float* __restrict__ pw,
                int npg, int k,
                const int* __restrict__ esrc_in, const int* __restrict__ edst_in,
                int* __restrict__ esrc_out, int* __restrict__ edst_out,
                unsigned short* __restrict__ Aout)   // [NB*k, 256]
{
    const int g   = blockIdx.x;
    const int tid = threadIdx.x;
    const int wv  = tid >> 6;
    const int ln  = tid & 63;

    __shared__ float muL[128], rsL[128], gmL[128], btL[128], pwL[128];
    __shared__ float scoreL[128], red[128];
    __shared__ int   mapL[128];
    __shared__ float sinv;

    if (tid < 128) {
        const float mu  = gsum[tid] / n_f;
        const float var = gsumsq[tid] / n_f - mu * mu;
        muL[tid] = mu;
        rsL[tid] = rsqrtf(var + 1e-5f);
        gmL[tid] = gamma[tid];
        btL[tid] = beta[tid];
        const float p = pw[tid];
        pwL[tid] = p;
        red[tid] = p * p;
    }
    __syncthreads();
    for (int off = 64; off > 0; off >>= 1) {
        if (tid < off) red[tid] += red[tid + off];
        __syncthreads();
    }
    if (tid == 0) sinv = rsqrtf(red[0]);
    __syncthreads();

    for (int r = wv; r < npg; r += 4) {
        const float* hr = h + (size_t)(g * npg + r) * H;
        float p = 0.f;
        #pragma unroll
        for (int half = 0; half < 2; ++half) {
            const int c = ln + half * 64;
            const float y = fmaxf(gmL[c] * (hr[c] - muL[c]) * rsL[c] + btL[c], 0.f);
            p += y * pwL[c];
        }
        #pragma unroll
        for (int off = 32; off > 0; off >>= 1)
            p += __shfl_down(p, off, 64);
        if (ln == 0) scoreL[r] = tanhf(p * sinv);
    }
    __syncthreads();

    if (tid < npg) {
        const float si = scoreL[tid];
        int cnt = 0;
        for (int j = 0; j < npg; ++j) {
            const float sj = scoreL[j];
            cnt += (sj > si) || (sj == si && j < tid);
        }
        mapL[tid] = (cnt < k) ? cnt : -1;
    }
    __syncthreads();

    // emit next-stage A' rows ([yh | yl], K2=256)
    for (int r = wv; r < npg; r += 4) {
        const int nr = mapL[r];
        if (nr < 0) continue;
        const float sc = scoreL[r];
        const float* hr = h + (size_t)(g * npg + r) * H;
        unsigned short* arow = Aout + (size_t)(g * k + nr) * 256;
        #pragma unroll
        for (int half = 0; half < 2; ++half) {
            const int c = ln + half * 64;
            const float y = fmaxf(gmL[c] * (hr[c] - muL[c]) * rsL[c] + btL[c], 0.f) * sc;
            const unsigned short hb = bf16_rne(y);
            const unsigned short lb = bf16_rne(y - bf16_to_f32(hb));
            arow[c] = hb; arow[128 + c] = lb;
        }
    }

    // remap this graph's 256 edges
    {
        const int e = g * EPG + tid;
        const int s = esrc_in[e];
        int ns = -1, nd = -1;
        if (s >= 0) {
            const int ms = mapL[s - g * npg];
            const int md = mapL[edst_in[e] - g * npg];
            if (ms >= 0 && md >= 0) { ns = g * k + ms; nd = g * k + md; }
        }
        esrc_out[e] = ns; edst_out[e] = nd;
    }
}

// ---------------------------------------------------------------------------
// fused_pool_final: stage-3 pool (npg=32,k=16) + mean-pool + MLP + sigmoid.
// [R6-verified]
// ---------------------------------------------------------------------------
__global__ __launch_bounds__(256)
void fused_pool_final(const float* __restrict__ h,
                      const float* __restrict__ gsum, const float* __restrict__ gsumsq,
                      float n_f,
                      const float* __restrict__ gamma, const float* __restrict__ beta,
                      const float* __restrict__ pw,
                      const float* __restrict__ lin1_w, const float* __restrict__ lin1_b,
                      const float* __restrict__ lin2_w, const float* __restrict__ lin2_b,
                      float* __restrict__ out)
{
    const int g   = blockIdx.x;
    const int tid = threadIdx.x;
    const int wv  = tid >> 6;
    const int ln  = tid & 63;
    const int npg = 32, k = 16;

    __shared__ float muL[128], rsL[128], gmL[128], btL[128], pwL[128];
    __shared__ float scoreL[32], red[128], gmean[128], h1c[64];
    __shared__ int   mapL[32];
    __shared__ float sinv;

    if (tid < 128) {
        const float mu  = gsum[tid] / n_f;
        const float var = gsumsq[tid] / n_f - mu * mu;
        muL[tid] = mu;
        rsL[tid] = rsqrtf(var + 1e-5f);
        gmL[tid] = gamma[tid];
        btL[tid] = beta[tid];
        const float p = pw[tid];
        pwL[tid] = p;
        red[tid] = p * p;
    }
    __syncthreads();
    for (int off = 64; off > 0; off >>= 1) {
        if (tid < off) red[tid] += red[tid + off];
        __syncthreads();
    }
    if (tid == 0) sinv = rsqrtf(red[0]);
    __syncthreads();

    for (int r = wv; r < npg; r += 4) {
        const float* hr = h + (size_t)(g * npg + r) * H;
        float p = 0.f;
        #pragma unroll
        for (int half = 0; half < 2; ++half) {
            const int c = ln + half * 64;
            const float y = fmaxf(gmL[c] * (hr[c] - muL[c]) * rsL[c] + btL[c], 0.f);
            p += y * pwL[c];
        }
        #pragma unroll
        for (int off = 32; off > 0; off >>= 1)
            p += __shfl_down(p, off, 64);
        if (ln == 0) scoreL[r] = tanhf(p * sinv);
    }
    __syncthreads();

    if (tid < npg) {
        const float si = scoreL[tid];
        int cnt = 0;
        for (int j = 0; j < npg; ++j) {
            const float sj = scoreL[j];
            cnt += (sj > si) || (sj == si && j < tid);
        }
        mapL[tid] = (cnt < k) ? cnt : -1;
    }
    __syncthreads();

    if (tid < 128) {
        float acc = 0.f;
        for (int r = 0; r < npg; ++r) {
            if (mapL[r] < 0) continue;
            const float hv = h[(size_t)(g * npg + r) * H + tid];
            const float y  = fmaxf(gmL[tid] * (hv - muL[tid]) * rsL[tid] + btL[tid], 0.f);
            acc += y * scoreL[r];
        }
        gmean[tid] = acc * (1.0f / 16.0f);
    }
    __syncthreads();

    if (tid < 64) {
        float acc = lin1_b[tid];
        for (int o = 0; o < 128; ++o) acc += gmean[o] * lin1_w[o * 64 + tid];
        h1c[tid] = fmaxf(acc, 0.f);
    }
    __syncthreads();
    if (tid == 0) {
        float z = lin2_b[0];
        for (int j = 0; j < 64; ++j) z += h1c[j] * lin2_w[j];
        out[g] = 1.0f / (1.0f + expf(-z));
    }
}

extern "C" void kernel_launch(void* const* d_in, const int* in_sizes, int n_in,
                              void* d_out, int out_size, void* d_ws, size_t ws_size,
                              hipStream_t stream)
{
    const float* x        = (const float*)d_in[0];
    const int*   ei       = (const int*)  d_in[1];
    const float* eattr    = (const float*)d_in[2];
    const float* nn1_w    = (const float*)d_in[4];
    const float* nn1_b    = (const float*)d_in[5];
    const float* root1    = (const float*)d_in[6];
    const float* bias1    = (const float*)d_in[7];
    const float* nn2_w    = (const float*)d_in[8];
    const float* nn2_b    = (const float*)d_in[9];
    const float* root2    = (const float*)d_in[10];
    const float* bias2    = (const float*)d_in[11];
    const float* nn3_w    = (const float*)d_in[12];
    const float* nn3_b    = (const float*)d_in[13];
    const float* root3    = (const float*)d_in[14];
    const float* bias3    = (const float*)d_in[15];
    const float* gamma1   = (const float*)d_in[16];
    const float* beta1    = (const float*)d_in[17];
    const float* gamma2   = (const float*)d_in[18];
    const float* beta2    = (const float*)d_in[19];
    const float* gamma3   = (const float*)d_in[20];
    const float* beta3    = (const float*)d_in[21];
    const float* pw1      = (const float*)d_in[22];
    const float* pw2      = (const float*)d_in[23];
    const float* pw3      = (const float*)d_in[24];
    const float* lin1_w   = (const float*)d_in[25];
    const float* lin1_b   = (const float*)d_in[26];
    const float* lin2_w   = (const float*)d_in[27];
    const float* lin2_b   = (const float*)d_in[28];

    const int* ei_src = ei;
    const int* ei_dst = ei + E_TOT;

    char* wp = (char*)d_ws;
    auto alloc = [&](size_t bytes) { char* p = wp; wp += (bytes + 255) & ~(size_t)255; return p; };
    float* h1    = (float*)alloc(4096 * 128 * 4);
    float* h2    = (float*)alloc(2048 * 128 * 4);
    float* h3    = (float*)alloc(1024 * 128 * 4);
    int*   src1  = (int*)alloc(E_TOT * 4);
    int*   dst1  = (int*)alloc(E_TOT * 4);
    int*   src2  = (int*)alloc(E_TOT * 4);
    int*   dst2  = (int*)alloc(E_TOT * 4);
    float* stats = (float*)alloc(6 * 128 * 4);
    unsigned short* A1  = (unsigned short*)alloc((size_t)4096 * 128 * 2);
    unsigned short* A2  = (unsigned short*)alloc((size_t)2048 * 256 * 2);
    unsigned short* A3  = (unsigned short*)alloc((size_t)1024 * 256 * 2);
    unsigned short* Bt1 = (unsigned short*)alloc((size_t)4352 * 128 * 2);
    unsigned short* Bt2 = (unsigned short*)alloc((size_t)4352 * 256 * 2);
    unsigned short* Bt3 = (unsigned short*)alloc((size_t)4352 * 256 * 2);
    float* Ybuf = (float*)alloc((size_t)4096 * YCOLS * 4);   // 69 MB

    hipMemsetAsync(stats, 0, 6 * 128 * sizeof(float), stream);

    // Setup (input transforms, no cross-stage deps)
    build_A<64><<<4096, 128, 0, stream>>>(x, A1);
    build_Bt<64> <<<dim3(34, 2), 256, 0, stream>>>(nn1_w, nn1_b, root1, Bt1);
    build_Bt<128><<<dim3(34, 4), 256, 0, stream>>>(nn2_w, nn2_b, root2, Bt2);
    build_Bt<128><<<dim3(34, 4), 256, 0, stream>>>(nn3_w, nn3_b, root3, Bt3);

    // ---- Stage 1 ----
    ygemm2<64><<<dim3(32, 17), 256, 0, stream>>>(A1, Bt1, Ybuf, bias1, h1);
    contract_edges<<<E_TOT / 8, 256, 0, stream>>>(Ybuf, eattr, ei_src, ei_dst, h1);
    bn_stats<<<64, 256, 0, stream>>>(h1, 4096, stats, stats + 128);
    fused_pool<<<NB, 256, 0, stream>>>(h1, stats, stats + 128, 4096.0f,
                                       gamma1, beta1, pw1, 128, 64,
                                       ei_src, ei_dst, src1, dst1, A2);

    // ---- Stage 2 ----
    ygemm2<128><<<dim3(16, 17), 256, 0, stream>>>(A2, Bt2, Ybuf, bias2, h2);
    contract_edges<<<E_TOT / 8, 256, 0, stream>>>(Ybuf, eattr, src1, dst1, h2);
    bn_stats<<<64, 256, 0, stream>>>(h2, 2048, stats + 256, stats + 384);
    fused_pool<<<NB, 256, 0, stream>>>(h2, stats + 256, stats + 384, 2048.0f,
                                       gamma2, beta2, pw2, 64, 32,
                                       src1, dst1, src2, dst2, A3);

    // ---- Stage 3 ----
    ygemm2<128><<<dim3(8, 17), 256, 0, stream>>>(A3, Bt3, Ybuf, bias3, h3);
    contract_edges<<<E_TOT / 8, 256, 0, stream>>>(Ybuf, eattr, src2, dst2, h3);
    bn_stats<<<64, 256, 0, stream>>>(h3, 1024, stats + 512, stats + 640);
    fused_pool_final<<<NB, 256, 0, stream>>>(h3, stats + 512, stats + 640, 1024.0f,
                                             gamma3, beta3, pw3,
                                             lin1_w, lin1_b, lin2_w, lin2_b,
                                             (float*)d_out);
}